// Round 2
// baseline (217.899 us; speedup 1.0000x reference)
//
#include <hip/hip_runtime.h>
#include <hip/hip_cooperative_groups.h>

namespace cg = cooperative_groups;

#define TT 1024
#define BB 4096
#define CHUNK 64
#define WH 64
#define NCH (TT / CHUNK)          // 16 chunks
#define NB  (NCH * BB)            // 65536 per plane

// workspace layout (float/dword indices)
#define WS_LOSS 0                 // float accumulator
#define WS_CNT  1                 // unsigned ticket counter
#define WS_A    64                // [16][4096] chunk affine A
#define WS_B    (WS_A + NB)       // [16][4096] chunk affine B

typedef float v2f __attribute__((ext_vector_type(2)));

struct StepC {
    v2f base01, base23, sw01, sw23;
    v2f c0_01, c0_23, c1_01, c1_23, c2_01, c2_23, c3_01, c3_23;
};

// r_j = (1-h_j)/2 state form; z' = S*(preact) folded so r = 1/(exp2(z)+1)
__device__ __forceinline__ StepC make_consts(const float* W_ih, const float* W_hh,
                                             const float* b_ih, const float* b_hh) {
    const float S = 2.8853900817779268f;   // 2*log2(e)
    float basev[4], swv[4], vv[4][4];
    #pragma unroll
    for (int jj = 0; jj < 4; ++jj) {
        float rowsum = W_hh[jj*4+0] + W_hh[jj*4+1] + W_hh[jj*4+2] + W_hh[jj*4+3];
        basev[jj] = S * (b_ih[jj] + b_hh[jj] + rowsum);
        swv[jj]   = S * W_ih[jj];
        #pragma unroll
        for (int kk = 0; kk < 4; ++kk) vv[jj][kk] = -2.f * S * W_hh[jj*4+kk];
    }
    StepC K;
    K.base01 = {basev[0], basev[1]}; K.base23 = {basev[2], basev[3]};
    K.sw01   = {swv[0],   swv[1]};   K.sw23   = {swv[2],   swv[3]};
    K.c0_01 = {vv[0][0], vv[1][0]};  K.c0_23 = {vv[2][0], vv[3][0]};
    K.c1_01 = {vv[0][1], vv[1][1]};  K.c1_23 = {vv[2][1], vv[3][1]};
    K.c2_01 = {vv[0][2], vv[1][2]};  K.c2_23 = {vv[2][2], vv[3][2]};
    K.c3_01 = {vv[0][3], vv[1][3]};  K.c3_23 = {vv[2][3], vv[3][3]};
    return K;
}

// one RNN step: 10 pk_fma + 4 exp2 + 4 rcp (trans pipe) + 4 adds
__device__ __forceinline__ void rnn_step(const StepC& K, float xf,
                                         float& r0, float& r1, float& r2, float& r3) {
    v2f xv  = {xf, xf};
    v2f r0b = {r0, r0}, r1b = {r1, r1}, r2b = {r2, r2}, r3b = {r3, r3};
    v2f z01 = __builtin_elementwise_fma(xv, K.sw01, K.base01);
    v2f z23 = __builtin_elementwise_fma(xv, K.sw23, K.base23);
    z01 = __builtin_elementwise_fma(r0b, K.c0_01, z01);
    z23 = __builtin_elementwise_fma(r0b, K.c0_23, z23);
    z01 = __builtin_elementwise_fma(r1b, K.c1_01, z01);
    z23 = __builtin_elementwise_fma(r1b, K.c1_23, z23);
    z01 = __builtin_elementwise_fma(r2b, K.c2_01, z01);
    z23 = __builtin_elementwise_fma(r2b, K.c2_23, z23);
    z01 = __builtin_elementwise_fma(r3b, K.c3_01, z01);
    z23 = __builtin_elementwise_fma(r3b, K.c3_23, z23);
    r0 = __builtin_amdgcn_rcpf(__builtin_amdgcn_exp2f(z01.x) + 1.0f);
    r1 = __builtin_amdgcn_rcpf(__builtin_amdgcn_exp2f(z01.y) + 1.0f);
    r2 = __builtin_amdgcn_rcpf(__builtin_amdgcn_exp2f(z23.x) + 1.0f);
    r3 = __builtin_amdgcn_rcpf(__builtin_amdgcn_exp2f(z23.y) + 1.0f);
}

// Single fused cooperative kernel:
//   Phase A: h-warmup + chunk affine (A,B); y loads hidden under acc steps.
//   grid.sync()
//   Phase B: exact latent compose + in-register replay + outputs + BCE.
//   Loss finalized via device-scope atomic + ticket (no reduce kernel).
__launch_bounds__(64, 1)
__global__ void bkt_fused(const float* __restrict__ x, const float* __restrict__ y,
                          const float* __restrict__ prior,
                          const float* __restrict__ W_ih, const float* __restrict__ W_hh,
                          const float* __restrict__ b_ih, const float* __restrict__ b_hh,
                          float* __restrict__ out, float* __restrict__ ws)
{
    const int lane = threadIdx.x;
    const int c  = blockIdx.x >> 6;        // chunk 0..15
    const int eg = blockIdx.x & 63;
    const int e  = eg * 64 + lane;
    const int t0 = c * CHUNK;
    const int t_start = (c == 0) ? 0 : (t0 - WH);
    const float* xp  = x + (size_t)t_start * BB + e;
    const float* ypb = y + (size_t)t0 * BB + e;

    // poison-safe init of loss accumulator + ticket, ordered by grid.sync
    if (blockIdx.x == 0 && lane == 0) {
        ws[WS_LOSS] = 0.0f;
        ((unsigned*)ws)[WS_CNT] = 0u;
    }

    float bufA[32], bufB[32];
    auto issueA = [&](const float* p) {
        #pragma unroll
        for (int i = 0; i < 32; ++i) bufA[i] = p[(size_t)i * BB];
    };
    auto issueB = [&](const float* p) {
        #pragma unroll
        for (int i = 0; i < 32; ++i) bufB[i] = p[(size_t)i * BB];
    };
    auto packA = [&]() -> unsigned {
        unsigned m = 0;
        #pragma unroll
        for (int i = 0; i < 32; ++i) if (bufA[i] != 0.0f) m |= (1u << i);
        return m;
    };
    auto packB = [&]() -> unsigned {
        unsigned m = 0;
        #pragma unroll
        for (int i = 0; i < 32; ++i) if (bufB[i] != 0.0f) m |= (1u << i);
        return m;
    };

    // first x words in flight before the (dependent-load) const setup
    issueA(xp); issueB(xp + (size_t)32 * BB);
    const float pr0 = prior[0];
    const StepC K = make_consts(W_ih, W_hh, b_ih, b_hh);

    float r0 = 0.5f, r1 = 0.5f, r2 = 0.5f, r3 = 0.5f;   // h = 0
    float A = 1.0f, Bacc = 0.0f;

    auto run32_warm = [&](unsigned m) {
        #pragma unroll 8
        for (int i = 0; i < 32; ++i)
            rnn_step(K, (float)((m >> i) & 1u), r0, r1, r2, r3);
    };
    auto run32_acc = [&](unsigned m) {
        #pragma unroll 8
        for (int i = 0; i < 32; ++i) {
            rnn_step(K, (float)((m >> i) & 1u), r0, r1, r2, r3);
            float a = (r0 + r1) - 1.0f;      // lat' = a*lat + b, b = 1-r0
            Bacc = fmaf(a, Bacc, 1.0f - r0);
            A *= a;
        }
    };

    float s0, s1, s2, s3;
    unsigned mo0, mo1, yw0, yw1;

    if (c == 0) {
        s0 = s1 = s2 = s3 = 0.5f;             // exact: h starts at 0
        mo0 = packA();
        issueA(ypb);                           // y word 0 hidden under acc
        run32_acc(mo0);
        mo1 = packB();
        issueB(ypb + (size_t)32 * BB);         // y word 1 hidden under acc
        run32_acc(mo1);
        yw0 = packA(); yw1 = packB();
    } else {
        unsigned mw0 = packA();
        issueA(xp + (size_t)64 * BB);          // out word 0 in flight during warm
        run32_warm(mw0);
        unsigned mw1 = packB();
        issueB(xp + (size_t)96 * BB);          // out word 1 in flight during warm
        run32_warm(mw1);
        s0 = r0; s1 = r1; s2 = r2; s3 = r3;    // state at t0 (kept in regs)
        mo0 = packA();
        issueA(ypb);
        run32_acc(mo0);
        mo1 = packB();
        issueB(ypb + (size_t)32 * BB);
        run32_acc(mo1);
        yw0 = packA(); yw1 = packB();
    }

    const int idx = c * BB + e;
    ws[WS_A + idx] = A;
    ws[WS_B + idx] = Bacc;

    __threadfence();
    cg::this_grid().sync();

    // ---- Phase B: compose exact chunk-entry latent from earlier chunks
    float Av[NCH - 1], Bv[NCH - 1];
    #pragma unroll
    for (int cc = 0; cc < NCH - 1; ++cc) {
        Av[cc] = ws[WS_A + cc * BB + e];
        Bv[cc] = ws[WS_B + cc * BB + e];
    }
    float lat = 1.0f / (1.0f + __builtin_amdgcn_exp2f(-1.4426950408889634f * pr0));
    #pragma unroll
    for (int cc = 0; cc < NCH - 1; ++cc)
        lat = (cc < c) ? fmaf(Av[cc], lat, Bv[cc]) : lat;

    // replay output steps from register-held state
    r0 = s0; r1 = s1; r2 = s2; r3 = s3;
    float* cO = out + (size_t)t0 * BB + e;
    float* lO = cO + (size_t)TT * BB;
    float lossAcc = 0.0f;

    auto outblock = [&](unsigned mw, unsigned yw, int tb) {
        float prod = 1.0f;
        #pragma unroll 8
        for (int i = 0; i < 32; ++i) {
            rnn_step(K, (float)((mw >> i) & 1u), r0, r1, r2, r3);
            float corr = fmaf(lat, (r2 + r3) - 1.0f, 1.0f - r2);
            float nl   = fmaf(lat, (r0 + r1) - 1.0f, 1.0f - r0);
            const size_t off = (size_t)(tb + i) * BB;
            cO[off] = corr;
            lO[off] = nl;
            float lp = ((yw >> i) & 1u) ? corr : (1.0f - corr);
            prod *= lp;
            if ((i & 7) == 7) {   // 8 likelihoods per log; >=0.015^8, no underflow
                lossAcc += __builtin_amdgcn_logf(prod) * 0.6931471805599453f;
                prod = 1.0f;
            }
            lat = nl;
        }
    };
    outblock(mo0, yw0, 0);
    outblock(mo1, yw1, 32);

    #pragma unroll
    for (int o = 32; o >= 1; o >>= 1) lossAcc += __shfl_xor(lossAcc, o, 64);

    if (lane == 0) {
        atomicAdd(&ws[WS_LOSS], lossAcc);
        __threadfence();
        unsigned t = atomicAdd(&((unsigned*)ws)[WS_CNT], 1u);
        if (t == (unsigned)(NCH * 64 - 1)) {            // last block finalizes
            float tot = atomicAdd(&ws[WS_LOSS], 0.0f);  // coherent read
            out[2 * (size_t)TT * BB] = tot * (-1.0f / ((float)TT * (float)BB));
        }
    }
}

extern "C" void kernel_launch(void* const* d_in, const int* in_sizes, int n_in,
                              void* d_out, int out_size, void* d_ws, size_t ws_size,
                              hipStream_t stream) {
    const float* x    = (const float*)d_in[0];
    const float* y    = (const float*)d_in[1];
    const float* pr   = (const float*)d_in[2];
    const float* W_ih = (const float*)d_in[3];
    const float* W_hh = (const float*)d_in[4];
    const float* b_ih = (const float*)d_in[5];
    const float* b_hh = (const float*)d_in[6];
    float* out = (float*)d_out;
    float* ws  = (float*)d_ws;   // loss/ticket + A/B planes (~512 KB)

    void* args[] = {(void*)&x, (void*)&y, (void*)&pr, (void*)&W_ih, (void*)&W_hh,
                    (void*)&b_ih, (void*)&b_hh, (void*)&out, (void*)&ws};
    hipLaunchCooperativeKernel((void*)bkt_fused, dim3(NCH * 64), dim3(64),
                               args, 0, stream);
}

// Round 3
// 168.224 us; speedup vs baseline: 1.2953x; 1.2953x over previous
//
#include <hip/hip_runtime.h>

#define TT 1024
#define BB 4096
#define CHUNK 64
#define WH 64
#define NCH (TT / CHUNK)          // 16 chunks
#define NB  (NCH * BB)            // 65536 per plane
#define MAGIC 0x1B7E9A3Du         // 4 distinct bytes; no memset poison can fake it

// workspace layout (float/dword indices)
#define WS_LOSSP 0                // [1024] per-block loss partials
#define WS_FLAG  1024             // [1024] uint publish flags (one per block)
#define WS_A     2048             // [16][4096] chunk affine A
#define WS_B     (WS_A + NB)      // [16][4096] chunk affine B

typedef float v2f __attribute__((ext_vector_type(2)));

struct StepC {
    v2f base01, base23, sw01, sw23;
    v2f c0_01, c0_23, c1_01, c1_23, c2_01, c2_23, c3_01, c3_23;
};

// r_j = (1-h_j)/2 state form; z' = S*(preact) folded so r = 1/(exp2(z)+1)
__device__ __forceinline__ StepC make_consts(const float* W_ih, const float* W_hh,
                                             const float* b_ih, const float* b_hh) {
    const float S = 2.8853900817779268f;   // 2*log2(e)
    float basev[4], swv[4], vv[4][4];
    #pragma unroll
    for (int jj = 0; jj < 4; ++jj) {
        float rowsum = W_hh[jj*4+0] + W_hh[jj*4+1] + W_hh[jj*4+2] + W_hh[jj*4+3];
        basev[jj] = S * (b_ih[jj] + b_hh[jj] + rowsum);
        swv[jj]   = S * W_ih[jj];
        #pragma unroll
        for (int kk = 0; kk < 4; ++kk) vv[jj][kk] = -2.f * S * W_hh[jj*4+kk];
    }
    StepC K;
    K.base01 = {basev[0], basev[1]}; K.base23 = {basev[2], basev[3]};
    K.sw01   = {swv[0],   swv[1]};   K.sw23   = {swv[2],   swv[3]};
    K.c0_01 = {vv[0][0], vv[1][0]};  K.c0_23 = {vv[2][0], vv[3][0]};
    K.c1_01 = {vv[0][1], vv[1][1]};  K.c1_23 = {vv[2][1], vv[3][1]};
    K.c2_01 = {vv[0][2], vv[1][2]};  K.c2_23 = {vv[2][2], vv[3][2]};
    K.c3_01 = {vv[0][3], vv[1][3]};  K.c3_23 = {vv[2][3], vv[3][3]};
    return K;
}

// one RNN step: 10 pk_fma + 4 exp2 + 4 rcp (trans pipe) + 4 adds
__device__ __forceinline__ void rnn_step(const StepC& K, float xf,
                                         float& r0, float& r1, float& r2, float& r3) {
    v2f xv  = {xf, xf};
    v2f r0b = {r0, r0}, r1b = {r1, r1}, r2b = {r2, r2}, r3b = {r3, r3};
    v2f z01 = __builtin_elementwise_fma(xv, K.sw01, K.base01);
    v2f z23 = __builtin_elementwise_fma(xv, K.sw23, K.base23);
    z01 = __builtin_elementwise_fma(r0b, K.c0_01, z01);
    z23 = __builtin_elementwise_fma(r0b, K.c0_23, z23);
    z01 = __builtin_elementwise_fma(r1b, K.c1_01, z01);
    z23 = __builtin_elementwise_fma(r1b, K.c1_23, z23);
    z01 = __builtin_elementwise_fma(r2b, K.c2_01, z01);
    z23 = __builtin_elementwise_fma(r2b, K.c2_23, z23);
    z01 = __builtin_elementwise_fma(r3b, K.c3_01, z01);
    z23 = __builtin_elementwise_fma(r3b, K.c3_23, z23);
    r0 = __builtin_amdgcn_rcpf(__builtin_amdgcn_exp2f(z01.x) + 1.0f);
    r1 = __builtin_amdgcn_rcpf(__builtin_amdgcn_exp2f(z01.y) + 1.0f);
    r2 = __builtin_amdgcn_rcpf(__builtin_amdgcn_exp2f(z23.x) + 1.0f);
    r3 = __builtin_amdgcn_rcpf(__builtin_amdgcn_exp2f(z23.y) + 1.0f);
}

// Single cooperative kernel, NO grid barrier:
//   Phase A: h-warmup + chunk affine (A,B); publish A/B via one release fence
//            + one sentinel flag store per block.
//   Sync:    per-eg flag spin (only on the 15 same-element sibling blocks).
//   Phase B: exact latent compose + in-register replay + outputs + BCE.
//   Loss: per-block partial store (no atomics); reduced by a tiny 2nd kernel.
__launch_bounds__(64, 1)
__global__ void bkt_fused(const float* __restrict__ x, const float* __restrict__ y,
                          const float* __restrict__ prior,
                          const float* __restrict__ W_ih, const float* __restrict__ W_hh,
                          const float* __restrict__ b_ih, const float* __restrict__ b_hh,
                          float* __restrict__ out, float* __restrict__ ws)
{
    const int lane = threadIdx.x;
    const int c  = blockIdx.x >> 6;        // chunk 0..15
    const int eg = blockIdx.x & 63;
    const int e  = eg * 64 + lane;
    const int t0 = c * CHUNK;
    const int t_start = (c == 0) ? 0 : (t0 - WH);
    const float* xp  = x + (size_t)t_start * BB + e;
    const float* ypb = y + (size_t)t0 * BB + e;

    float bufA[32], bufB[32];
    auto issueA = [&](const float* p) {
        #pragma unroll
        for (int i = 0; i < 32; ++i) bufA[i] = p[(size_t)i * BB];
    };
    auto issueB = [&](const float* p) {
        #pragma unroll
        for (int i = 0; i < 32; ++i) bufB[i] = p[(size_t)i * BB];
    };
    auto packA = [&]() -> unsigned {
        unsigned m = 0;
        #pragma unroll
        for (int i = 0; i < 32; ++i) if (bufA[i] != 0.0f) m |= (1u << i);
        return m;
    };
    auto packB = [&]() -> unsigned {
        unsigned m = 0;
        #pragma unroll
        for (int i = 0; i < 32; ++i) if (bufB[i] != 0.0f) m |= (1u << i);
        return m;
    };

    // first x words in flight before the (dependent-load) const setup
    issueA(xp); issueB(xp + (size_t)32 * BB);
    const float pr0 = prior[0];
    const StepC K = make_consts(W_ih, W_hh, b_ih, b_hh);

    float r0 = 0.5f, r1 = 0.5f, r2 = 0.5f, r3 = 0.5f;   // h = 0
    float A = 1.0f, Bacc = 0.0f;

    auto run32_warm = [&](unsigned m) {
        #pragma unroll 8
        for (int i = 0; i < 32; ++i)
            rnn_step(K, (float)((m >> i) & 1u), r0, r1, r2, r3);
    };
    auto run32_acc = [&](unsigned m) {
        #pragma unroll 8
        for (int i = 0; i < 32; ++i) {
            rnn_step(K, (float)((m >> i) & 1u), r0, r1, r2, r3);
            float a = (r0 + r1) - 1.0f;      // lat' = a*lat + b, b = 1-r0
            Bacc = fmaf(a, Bacc, 1.0f - r0);
            A *= a;
        }
    };

    float s0, s1, s2, s3;
    unsigned mo0, mo1, yw0, yw1;

    if (c == 0) {
        s0 = s1 = s2 = s3 = 0.5f;             // exact: h starts at 0
        mo0 = packA();
        issueA(ypb);                           // y word 0 hidden under acc
        run32_acc(mo0);
        mo1 = packB();
        issueB(ypb + (size_t)32 * BB);         // y word 1 hidden under acc
        run32_acc(mo1);
        yw0 = packA(); yw1 = packB();
    } else {
        unsigned mw0 = packA();
        issueA(xp + (size_t)64 * BB);          // out word 0 in flight during warm
        run32_warm(mw0);
        unsigned mw1 = packB();
        issueB(xp + (size_t)96 * BB);          // out word 1 in flight during warm
        run32_warm(mw1);
        s0 = r0; s1 = r1; s2 = r2; s3 = r3;    // state at t0 (kept in regs)
        mo0 = packA();
        issueA(ypb);
        run32_acc(mo0);
        mo1 = packB();
        issueB(ypb + (size_t)32 * BB);
        run32_acc(mo1);
        yw0 = packA(); yw1 = packB();
    }

    // ---- publish this chunk's affine (A,B): single-wave block, so one
    // lane-0 release fence orders all 64 lanes' stores before the flag.
    const int idx = c * BB + e;
    ws[WS_A + idx] = A;
    ws[WS_B + idx] = Bacc;
    __builtin_amdgcn_fence(__ATOMIC_RELEASE, "agent");
    if (lane == 0)
        __hip_atomic_store(&((unsigned*)ws)[WS_FLAG + blockIdx.x], MAGIC,
                           __ATOMIC_RELAXED, __HIP_MEMORY_SCOPE_AGENT);

    // ---- wait only for same-eg siblings with cc < c (chunk-0 never waits;
    // co-residency guaranteed by cooperative launch -> no deadlock)
    float lat = 1.0f / (1.0f + __builtin_amdgcn_exp2f(-1.4426950408889634f * pr0));
    if (c > 0) {
        const unsigned* fl = (const unsigned*)ws + WS_FLAG + eg;
        for (int cc = 0; cc < c; ++cc) {
            while (__hip_atomic_load(&fl[(size_t)cc * 64], __ATOMIC_RELAXED,
                                     __HIP_MEMORY_SCOPE_AGENT) != MAGIC)
                __builtin_amdgcn_s_sleep(1);
        }
        __builtin_amdgcn_fence(__ATOMIC_ACQUIRE, "agent");
        #pragma unroll 1
        for (int cc = 0; cc < c; ++cc) {
            float Ac = ws[WS_A + cc * BB + e];
            float Bc = ws[WS_B + cc * BB + e];
            lat = fmaf(Ac, lat, Bc);
        }
    }

    // ---- Phase B: replay output steps from register-held state
    r0 = s0; r1 = s1; r2 = s2; r3 = s3;
    float* cO = out + (size_t)t0 * BB + e;
    float* lO = cO + (size_t)TT * BB;
    float lossAcc = 0.0f;

    auto outblock = [&](unsigned mw, unsigned yw, int tb) {
        float prod = 1.0f;
        #pragma unroll 8
        for (int i = 0; i < 32; ++i) {
            rnn_step(K, (float)((mw >> i) & 1u), r0, r1, r2, r3);
            float corr = fmaf(lat, (r2 + r3) - 1.0f, 1.0f - r2);
            float nl   = fmaf(lat, (r0 + r1) - 1.0f, 1.0f - r0);
            const size_t off = (size_t)(tb + i) * BB;
            cO[off] = corr;
            lO[off] = nl;
            float lp = ((yw >> i) & 1u) ? corr : (1.0f - corr);
            prod *= lp;
            if ((i & 7) == 7) {   // 8 likelihoods per log; >=0.015^8, no underflow
                lossAcc += __builtin_amdgcn_logf(prod) * 0.6931471805599453f;
                prod = 1.0f;
            }
            lat = nl;
        }
    };
    outblock(mo0, yw0, 0);
    outblock(mo1, yw1, 32);

    #pragma unroll
    for (int o = 32; o >= 1; o >>= 1) lossAcc += __shfl_xor(lossAcc, o, 64);
    if (lane == 0) ws[WS_LOSSP + blockIdx.x] = lossAcc;   // plain store; next kernel reads
}

// Reduce 1024 per-block partials -> final mean NLL
__global__ void reduce_k(const float* __restrict__ part, float* __restrict__ loss) {
    float acc = 0.f;
    for (int i = threadIdx.x; i < 1024; i += 256) acc += part[i];
    #pragma unroll
    for (int o = 32; o >= 1; o >>= 1) acc += __shfl_xor(acc, o, 64);
    __shared__ float w[4];
    if ((threadIdx.x & 63) == 0) w[threadIdx.x >> 6] = acc;
    __syncthreads();
    if (threadIdx.x == 0) {
        float t = w[0] + w[1] + w[2] + w[3];
        *loss = t * (-1.0f / ((float)TT * (float)BB));
    }
}

extern "C" void kernel_launch(void* const* d_in, const int* in_sizes, int n_in,
                              void* d_out, int out_size, void* d_ws, size_t ws_size,
                              hipStream_t stream) {
    const float* x    = (const float*)d_in[0];
    const float* y    = (const float*)d_in[1];
    const float* pr   = (const float*)d_in[2];
    const float* W_ih = (const float*)d_in[3];
    const float* W_hh = (const float*)d_in[4];
    const float* b_ih = (const float*)d_in[5];
    const float* b_hh = (const float*)d_in[6];
    float* out = (float*)d_out;
    float* ws  = (float*)d_ws;   // lossPart + flags + A/B planes (~532 KB)

    void* args[] = {(void*)&x, (void*)&y, (void*)&pr, (void*)&W_ih, (void*)&W_hh,
                    (void*)&b_ih, (void*)&b_hh, (void*)&out, (void*)&ws};
    hipLaunchCooperativeKernel((void*)bkt_fused, dim3(NCH * 64), dim3(64),
                               args, 0, stream);
    reduce_k<<<1, 256, 0, stream>>>(ws, out + 2 * (size_t)TT * BB);
}

// Round 4
// 114.908 us; speedup vs baseline: 1.8963x; 1.4640x over previous
//
#include <hip/hip_runtime.h>

#define TT 1024
#define BB 4096
#define CHUNK 64
#define WH 64
#define NCH (TT / CHUNK)          // 16 chunks
#define NB  (NCH * BB)            // 65536 per plane

// workspace layout (float/dword indices)
#define WS_LOSSP 0                // [1024] per-block loss partials
#define WS_A     1024             // [16][4096] chunk affine A
#define WS_B     (WS_A + NB)      // [16][4096] chunk affine B
#define WS_H     (WS_B + NB)      // [4][16][4096] r-state at chunk start
#define WS_XW    (WS_H + 4 * NB)  // [2][16][4096] packed x output words (uint)
#define WS_YW    (WS_XW + 2 * NB) // [2][16][4096] packed y output words (uint)

typedef float v2f __attribute__((ext_vector_type(2)));

struct StepC {
    v2f base01, base23, sw01, sw23;
    v2f c0_01, c0_23, c1_01, c1_23, c2_01, c2_23, c3_01, c3_23;
};

// r_j = (1-h_j)/2 state form; z' = S*(preact) folded so r = 1/(exp2(z)+1)
__device__ __forceinline__ StepC make_consts(const float* W_ih, const float* W_hh,
                                             const float* b_ih, const float* b_hh) {
    const float S = 2.8853900817779268f;   // 2*log2(e)
    float basev[4], swv[4], vv[4][4];
    #pragma unroll
    for (int jj = 0; jj < 4; ++jj) {
        float rowsum = W_hh[jj*4+0] + W_hh[jj*4+1] + W_hh[jj*4+2] + W_hh[jj*4+3];
        basev[jj] = S * (b_ih[jj] + b_hh[jj] + rowsum);
        swv[jj]   = S * W_ih[jj];
        #pragma unroll
        for (int kk = 0; kk < 4; ++kk) vv[jj][kk] = -2.f * S * W_hh[jj*4+kk];
    }
    StepC K;
    K.base01 = {basev[0], basev[1]}; K.base23 = {basev[2], basev[3]};
    K.sw01   = {swv[0],   swv[1]};   K.sw23   = {swv[2],   swv[3]};
    K.c0_01 = {vv[0][0], vv[1][0]};  K.c0_23 = {vv[2][0], vv[3][0]};
    K.c1_01 = {vv[0][1], vv[1][1]};  K.c1_23 = {vv[2][1], vv[3][1]};
    K.c2_01 = {vv[0][2], vv[1][2]};  K.c2_23 = {vv[2][2], vv[3][2]};
    K.c3_01 = {vv[0][3], vv[1][3]};  K.c3_23 = {vv[2][3], vv[3][3]};
    return K;
}

// one RNN step: 10 pk_fma + 4 exp2 + 4 rcp (trans pipe) + 4 adds
__device__ __forceinline__ void rnn_step(const StepC& K, float xf,
                                         float& r0, float& r1, float& r2, float& r3) {
    v2f xv  = {xf, xf};
    v2f r0b = {r0, r0}, r1b = {r1, r1}, r2b = {r2, r2}, r3b = {r3, r3};
    v2f z01 = __builtin_elementwise_fma(xv, K.sw01, K.base01);
    v2f z23 = __builtin_elementwise_fma(xv, K.sw23, K.base23);
    z01 = __builtin_elementwise_fma(r0b, K.c0_01, z01);
    z23 = __builtin_elementwise_fma(r0b, K.c0_23, z23);
    z01 = __builtin_elementwise_fma(r1b, K.c1_01, z01);
    z23 = __builtin_elementwise_fma(r1b, K.c1_23, z23);
    z01 = __builtin_elementwise_fma(r2b, K.c2_01, z01);
    z23 = __builtin_elementwise_fma(r2b, K.c2_23, z23);
    z01 = __builtin_elementwise_fma(r3b, K.c3_01, z01);
    z23 = __builtin_elementwise_fma(r3b, K.c3_23, z23);
    r0 = __builtin_amdgcn_rcpf(__builtin_amdgcn_exp2f(z01.x) + 1.0f);
    r1 = __builtin_amdgcn_rcpf(__builtin_amdgcn_exp2f(z01.y) + 1.0f);
    r2 = __builtin_amdgcn_rcpf(__builtin_amdgcn_exp2f(z23.x) + 1.0f);
    r3 = __builtin_amdgcn_rcpf(__builtin_amdgcn_exp2f(z23.y) + 1.0f);
}

// ---------------- Pass 1: h-warmup + chunk affine (A,B) + x/y bit-pack ----------------
// Software-pipelined: next word's 32 loads are in flight while the current
// word's 32 RNN steps run. y loads hide under the acc-step compute.
__launch_bounds__(64, 1)
__global__ void bkt_pass1(const float* __restrict__ x, const float* __restrict__ y,
                          const float* __restrict__ W_ih, const float* __restrict__ W_hh,
                          const float* __restrict__ b_ih, const float* __restrict__ b_hh,
                          float* __restrict__ ws)
{
    const int lane = threadIdx.x;
    const int c  = blockIdx.x >> 6;        // chunk 0..15
    const int eg = blockIdx.x & 63;
    const int e  = eg * 64 + lane;
    const int t0 = c * CHUNK;
    const int t_start = (c == 0) ? 0 : (t0 - WH);
    const float* xp  = x + (size_t)t_start * BB + e;
    const float* ypb = y + (size_t)t0 * BB + e;

    float bufA[32], bufB[32];
    auto issueA = [&](const float* p) {
        #pragma unroll
        for (int i = 0; i < 32; ++i) bufA[i] = p[(size_t)i * BB];
    };
    auto issueB = [&](const float* p) {
        #pragma unroll
        for (int i = 0; i < 32; ++i) bufB[i] = p[(size_t)i * BB];
    };
    auto packA = [&]() -> unsigned {
        unsigned m = 0;
        #pragma unroll
        for (int i = 0; i < 32; ++i) if (bufA[i] != 0.0f) m |= (1u << i);
        return m;
    };
    auto packB = [&]() -> unsigned {
        unsigned m = 0;
        #pragma unroll
        for (int i = 0; i < 32; ++i) if (bufB[i] != 0.0f) m |= (1u << i);
        return m;
    };

    // first x words in flight before the (dependent-load) const setup
    issueA(xp); issueB(xp + (size_t)32 * BB);
    const StepC K = make_consts(W_ih, W_hh, b_ih, b_hh);

    float r0 = 0.5f, r1 = 0.5f, r2 = 0.5f, r3 = 0.5f;   // h = 0
    float A = 1.0f, Bacc = 0.0f;

    auto run32_warm = [&](unsigned m) {
        #pragma unroll 8
        for (int i = 0; i < 32; ++i)
            rnn_step(K, (float)((m >> i) & 1u), r0, r1, r2, r3);
    };
    auto run32_acc = [&](unsigned m) {
        #pragma unroll 8
        for (int i = 0; i < 32; ++i) {
            rnn_step(K, (float)((m >> i) & 1u), r0, r1, r2, r3);
            float a = (r0 + r1) - 1.0f;      // lat' = a*lat + b, b = 1-r0
            Bacc = fmaf(a, Bacc, 1.0f - r0);
            A *= a;
        }
    };

    float s0, s1, s2, s3;
    unsigned mo0, mo1, yw0, yw1;

    if (c == 0) {
        s0 = s1 = s2 = s3 = 0.5f;             // exact: h starts at 0
        mo0 = packA();
        issueA(ypb);                           // y word 0 hidden under acc
        run32_acc(mo0);
        mo1 = packB();
        issueB(ypb + (size_t)32 * BB);         // y word 1 hidden under acc
        run32_acc(mo1);
        yw0 = packA(); yw1 = packB();
    } else {
        unsigned mw0 = packA();
        issueA(xp + (size_t)64 * BB);          // out word 0 in flight during warm
        run32_warm(mw0);
        unsigned mw1 = packB();
        issueB(xp + (size_t)96 * BB);          // out word 1 in flight during warm
        run32_warm(mw1);
        s0 = r0; s1 = r1; s2 = r2; s3 = r3;    // state at t0
        mo0 = packA();
        issueA(ypb);                           // y word 0 hidden under acc
        run32_acc(mo0);
        mo1 = packB();
        issueB(ypb + (size_t)32 * BB);         // y word 1 hidden under acc
        run32_acc(mo1);
        yw0 = packA(); yw1 = packB();
    }

    const int idx = c * BB + e;
    ws[WS_A + idx] = A;
    ws[WS_B + idx] = Bacc;
    ws[WS_H + 0 * NB + idx] = s0;
    ws[WS_H + 1 * NB + idx] = s1;
    ws[WS_H + 2 * NB + idx] = s2;
    ws[WS_H + 3 * NB + idx] = s3;
    unsigned* wsu = (unsigned*)ws;
    wsu[WS_XW + 0 * NB + idx] = mo0;
    wsu[WS_XW + 1 * NB + idx] = mo1;
    wsu[WS_YW + 0 * NB + idx] = yw0;
    wsu[WS_YW + 1 * NB + idx] = yw1;
}

// ---------------- Pass 2: exact latent compose + replay + outputs ----------------
// All inputs are small packed/coalesced ws reads (38 dwords/lane); no wide
// strided global loads at the head.
__launch_bounds__(64, 1)
__global__ void bkt_pass2(const float* __restrict__ prior,
                          const float* __restrict__ W_ih, const float* __restrict__ W_hh,
                          const float* __restrict__ b_ih, const float* __restrict__ b_hh,
                          float* __restrict__ out, float* __restrict__ ws)
{
    const int lane = threadIdx.x;
    const int c  = blockIdx.x >> 6;
    const int eg = blockIdx.x & 63;
    const int e  = eg * 64 + lane;
    const int t0 = c * CHUNK;
    const int idx = c * BB + e;

    // issue all loads up front (independent, coalesced)
    float Av[NCH - 1], Bv[NCH - 1];
    #pragma unroll
    for (int cc = 0; cc < NCH - 1; ++cc) {
        Av[cc] = ws[WS_A + cc * BB + e];
        Bv[cc] = ws[WS_B + cc * BB + e];
    }
    float r0 = ws[WS_H + 0 * NB + idx];
    float r1 = ws[WS_H + 1 * NB + idx];
    float r2 = ws[WS_H + 2 * NB + idx];
    float r3 = ws[WS_H + 3 * NB + idx];
    const unsigned* wsu = (const unsigned*)ws;
    unsigned mo0 = wsu[WS_XW + 0 * NB + idx];
    unsigned mo1 = wsu[WS_XW + 1 * NB + idx];
    unsigned yw0 = wsu[WS_YW + 0 * NB + idx];
    unsigned yw1 = wsu[WS_YW + 1 * NB + idx];
    const float pr0 = prior[0];

    const StepC K = make_consts(W_ih, W_hh, b_ih, b_hh);

    // exact chunk-entry latent via affine composition
    float lat = 1.0f / (1.0f + __builtin_amdgcn_exp2f(-1.4426950408889634f * pr0));
    #pragma unroll
    for (int cc = 0; cc < NCH - 1; ++cc)
        lat = (cc < c) ? fmaf(Av[cc], lat, Bv[cc]) : lat;

    float* cO = out + (size_t)t0 * BB + e;
    float* lO = cO + (size_t)TT * BB;
    float lossAcc = 0.0f;

    auto outblock = [&](unsigned mw, unsigned yw, int tb) {
        float prod = 1.0f;
        #pragma unroll 8
        for (int i = 0; i < 32; ++i) {
            rnn_step(K, (float)((mw >> i) & 1u), r0, r1, r2, r3);
            float corr = fmaf(lat, (r2 + r3) - 1.0f, 1.0f - r2);
            float nl   = fmaf(lat, (r0 + r1) - 1.0f, 1.0f - r0);
            const size_t off = (size_t)(tb + i) * BB;
            cO[off] = corr;
            lO[off] = nl;
            float lp = ((yw >> i) & 1u) ? corr : (1.0f - corr);
            prod *= lp;
            if ((i & 7) == 7) {   // 8 likelihoods per log; >=0.015^8, no underflow
                lossAcc += __builtin_amdgcn_logf(prod) * 0.6931471805599453f;
                prod = 1.0f;
            }
            lat = nl;
        }
    };
    outblock(mo0, yw0, 0);
    outblock(mo1, yw1, 32);

    #pragma unroll
    for (int o = 32; o >= 1; o >>= 1) lossAcc += __shfl_xor(lossAcc, o, 64);
    if (lane == 0) ws[WS_LOSSP + blockIdx.x] = lossAcc;
}

// Reduce 1024 per-block partials -> final mean NLL
__global__ void reduce_k(const float* __restrict__ part, float* __restrict__ loss) {
    float acc = 0.f;
    for (int i = threadIdx.x; i < 1024; i += 256) acc += part[i];
    #pragma unroll
    for (int o = 32; o >= 1; o >>= 1) acc += __shfl_xor(acc, o, 64);
    __shared__ float w[4];
    if ((threadIdx.x & 63) == 0) w[threadIdx.x >> 6] = acc;
    __syncthreads();
    if (threadIdx.x == 0) {
        float t = w[0] + w[1] + w[2] + w[3];
        *loss = t * (-1.0f / ((float)TT * (float)BB));
    }
}

extern "C" void kernel_launch(void* const* d_in, const int* in_sizes, int n_in,
                              void* d_out, int out_size, void* d_ws, size_t ws_size,
                              hipStream_t stream) {
    const float* x    = (const float*)d_in[0];
    const float* y    = (const float*)d_in[1];
    const float* pr   = (const float*)d_in[2];
    const float* W_ih = (const float*)d_in[3];
    const float* W_hh = (const float*)d_in[4];
    const float* b_ih = (const float*)d_in[5];
    const float* b_hh = (const float*)d_in[6];
    float* out = (float*)d_out;
    float* ws  = (float*)d_ws;   // lossPart + A/B/H/XW/YW planes (~2.6 MB)

    bkt_pass1<<<NCH * 64, 64, 0, stream>>>(x, y, W_ih, W_hh, b_ih, b_hh, ws);
    bkt_pass2<<<NCH * 64, 64, 0, stream>>>(pr, W_ih, W_hh, b_ih, b_hh, out, ws);
    reduce_k<<<1, 256, 0, stream>>>(ws, out + 2 * (size_t)TT * BB);
}